// Round 9
// baseline (985.444 us; speedup 1.0000x reference)
//
#include <hip/hip_runtime.h>

#define NB 16
#define LT 4096
#define ND 512
#define MBINS 1024
#define LMBDA 0.1f
#define DLB 4                 // d-channels per fwd block (accumulators: 4 bins x 2 = 16 floats)
#define FWD_THREADS 1024

__device__ __forceinline__ float2 cmulf(float2 a, float2 b) {
    return make_float2(a.x * b.x - a.y * b.y, a.x * b.y + a.y * b.x);
}
__device__ __forceinline__ float2 caddf(float2 a, float2 b) { return make_float2(a.x + b.x, a.y + b.y); }
__device__ __forceinline__ float2 csubf(float2 a, float2 b) { return make_float2(a.x - b.x, a.y - b.y); }

// base-4 digit reversal of an 8-bit (4-digit) index
__device__ __forceinline__ int rev4_8(int k) {
    return ((k & 3) << 6) | ((k & 12) << 2) | ((k >> 2) & 12) | ((k >> 6) & 3);
}
// base-4 digit reversal of a 12-bit index
__device__ __forceinline__ int rev4_12(int t) {
    unsigned r = __brev((unsigned)t) >> 20;
    return (int)(((r & 0x555u) << 1) | ((r >> 1) & 0x555u));
}

// ws layout: float [4][NB][MBINS] : 0 -> sum|Qa|^2, 1 -> sum|Qb|^2, 2 -> Re C, 3 -> Im C
// where C = sum_d conj(Qa)*Qb.

// Forward: block = (batch, 4 consecutive d), 1024 threads. Real-pack z = a + i*b.
// 4096-pt FFT via 4x radix-4 1024-pt DIF sub-FFTs (t2 decimation). Stages m=256..4 in
// LDS (1 butterfly/thread/stage, all at the b64 bank floor); final m=1 stage in
// registers, accumulating X[m] (+= W4096^{t2 m} * Y) and mirror X[3072+m]
// (+= i^{t2} * same product). One end-of-kernel LDS exchange pairs (X[k], X[4096-k]).
// Per-thread accumulators: 4 bins x (X1,G) = 16 floats -> no spill at 64 VGPRs
// (R8's 8-bin variant spilled all 32 accumulator floats; that was the 2x regression).
__global__ __launch_bounds__(FWD_THREADS)
void cte_fwd_kernel(const float* __restrict__ A, const float* __restrict__ Bp,
                    float* __restrict__ ws) {
    __shared__ float2 z[4096];         // [1024 rows][4 cols]; 32 KB
    __shared__ float2 tw[256];         // tw[e] = exp(-2*pi*i*e/1024), e<256

    const int tid = threadIdx.x;
    // XCD-aware swizzle: the 4 chunks sharing each 64B line become launch-adjacent on
    // one XCD -> L2/L3 dedup of the 16B-granular row reads. 2048 % 8 == 0 (bijective).
    const int logical = (blockIdx.x & 7) * (gridDim.x >> 3) + (blockIdx.x >> 3);
    const int bb    = logical >> 7;           // 16 batches
    const int chunk = logical & 127;          // 128 d-chunks of 4
    const int d0    = chunk * DLB;

    if (tid < 256) {
        float s, c;
        sincosf(-6.283185307179586f * (float)tid * (1.0f / 1024.0f), &s, &c);
        tw[tid] = make_float2(c, s);
    }

    const int dl  = tid & 3;          // d lane
    const int bf  = tid >> 2;         // butterfly id [0,256) (same for all stages)
    const int rb0 = rev4_8(bf);       // owned-bin base: bins m = 256q + rb0

    float2 X1[4], G[4];               // X[m] and X[3072+m], m = 256q + rb0
#pragma unroll
    for (int i = 0; i < 4; ++i) {
        X1[i] = make_float2(0.f, 0.f);
        G[i]  = make_float2(0.f, 0.f);
    }

    for (int t2 = 0; t2 < 4; ++t2) {
        __syncthreads();  // previous round's m=1 reads of z done; tw valid (round 0)

        // ---- coalesced load of subsequence x[4*t1 + t2], 4 d-channels ----
        // One float4 LDS write per item: banks 4l..4l+3 mod 32 -> conflict-free.
#pragma unroll
        for (int it = 0; it < 2; ++it) {
            int p  = it * FWD_THREADS + tid;   // 2048 items: 1024 t1 x 2 d-pairs
            int dp = p & 1;
            int t1 = p >> 1;
            size_t off = ((size_t)(bb * LT + 4 * t1 + t2)) * ND + d0 + 2 * dp;
            float2 av = *(const float2*)(A + off);
            float2 bv = *(const float2*)(Bp + off);
            *(float4*)&z[(t1 << 2) + 2 * dp] = make_float4(av.x, bv.x, av.y, bv.y);
        }
        __syncthreads();

        // ---- radix-4 DIF stages m=256,64,16,4 in LDS (1 butterfly/thread) ----
#pragma unroll
        for (int st = 0; st < 4; ++st) {
            const int lgm  = 8 - 2 * st;      // 8,6,4,2
            const int m    = 1 << lgm;
            const int step = 256 >> lgm;      // 1024/(4m)
            int j  = bf & (m - 1);
            int i0 = ((bf >> lgm) << (lgm + 2)) + j;
            int ix = (i0 << 2) + dl;          // rows +m,+2m,+3m -> imm offsets
            float2 a0 = z[ix];
            float2 a1 = z[ix + 4 * m];
            float2 a2 = z[ix + 8 * m];
            float2 a3 = z[ix + 12 * m];
            float2 t0  = caddf(a0, a2), t1v = csubf(a0, a2);
            float2 t2v = caddf(a1, a3), t3  = csubf(a1, a3);
            float2 w1 = tw[j * step];
            float2 w2 = cmulf(w1, w1);
            float2 w3 = cmulf(w2, w1);
            z[ix]          = caddf(t0, t2v);
            z[ix + 4 * m]  = cmulf(make_float2(t1v.x + t3.y, t1v.y - t3.x), w1);
            z[ix + 8 * m]  = cmulf(csubf(t0, t2v), w2);
            z[ix + 12 * m] = cmulf(make_float2(t1v.x - t3.y, t1v.y + t3.x), w3);
            __syncthreads();
        }

        // ---- final stage (m=1) in registers + bin accumulation ----
        // w(m) = W4096^{t2*m}, m = 256q + rb0: w = wr * w16^q,
        //   wr = W^(t2*rb0), w16 = W^(256 t2). Mirror: X[3072+m] += i^{t2} * (w*y).
        float2 wr, w16;
        {
            float s, c;
            sincosf(-1.5339807878856412e-03f * (float)(t2 * rb0), &s, &c);  // -2pi/4096*t2*rb0
            wr = make_float2(c, s);
            sincosf(-3.9269908169872414e-01f * (float)t2, &s, &c);          // -2pi/16 * t2
            w16 = make_float2(c, s);
        }
        const float mix = (t2 & 1) ? 0.f : ((t2 & 2) ? -1.f : 1.f);  // Re i^{t2}
        const float miy = (t2 & 1) ? ((t2 & 2) ? -1.f : 1.f) : 0.f;  // Im i^{t2}

        {
            int ix = (bf << 4) + dl;          // row 4*bf, col dl (4x bank aliasing; rare)
            float2 a0 = z[ix];
            float2 a1 = z[ix + 4];
            float2 a2 = z[ix + 8];
            float2 a3 = z[ix + 12];
            float2 t0  = caddf(a0, a2), t1v = csubf(a0, a2);
            float2 t2v = caddf(a1, a3), t3  = csubf(a1, a3);
            float2 wb = wr;
            // q=0: y = t0 + t2v
            {
                float2 p = cmulf(wb, caddf(t0, t2v));
                X1[0] = caddf(X1[0], p);
                G[0].x += mix * p.x - miy * p.y;  G[0].y += mix * p.y + miy * p.x;
                wb = cmulf(wb, w16);
            }
            // q=1: y = t1 - i*t3
            {
                float2 p = cmulf(wb, make_float2(t1v.x + t3.y, t1v.y - t3.x));
                X1[1] = caddf(X1[1], p);
                G[1].x += mix * p.x - miy * p.y;  G[1].y += mix * p.y + miy * p.x;
                wb = cmulf(wb, w16);
            }
            // q=2: y = t0 - t2v
            {
                float2 p = cmulf(wb, csubf(t0, t2v));
                X1[2] = caddf(X1[2], p);
                G[2].x += mix * p.x - miy * p.y;  G[2].y += mix * p.y + miy * p.x;
                wb = cmulf(wb, w16);
            }
            // q=3: y = t1 + i*t3
            {
                float2 p = cmulf(wb, make_float2(t1v.x - t3.y, t1v.y + t3.x));
                X1[3] = caddf(X1[3], p);
                G[3].x += mix * p.x - miy * p.y;  G[3].y += mix * p.y + miy * p.x;
            }
        }
    }

    // ---- mirror exchange: X1[m] -> LDS, read partner X[k0], products, reduce, flush ----
    __syncthreads();   // all m=1 reads of z complete before overwrite
#pragma unroll
    for (int q = 0; q < 4; ++q) {
        int mbin = 256 * q + rb0;
        z[(mbin << 2) + dl] = X1[q];
    }
    __syncthreads();
#pragma unroll
    for (int q = 0; q < 4; ++q) {
        int mbin = 256 * q + rb0;
        int k0   = (1024 - mbin) & 1023;           // output bin
        float2 P  = z[(k0 << 2) + dl];             // X[k0]
        float2 Xm = (mbin == 0) ? P : G[q];        // X[4096-k0] (k0=0 self-mirror)
        float Ar = 0.5f * (P.x + Xm.x);
        float Ai = 0.5f * (P.y - Xm.y);
        float Br = 0.5f * (P.y + Xm.y);
        float Bi = 0.5f * (Xm.x - P.x);
        float da = Ar * Ar + Ai * Ai;
        float db = Br * Br + Bi * Bi;
        float cr = Ar * Br + Ai * Bi;
        float ci = Ar * Bi - Ai * Br;
        for (int msk = 1; msk < DLB; msk <<= 1) {
            da += __shfl_xor(da, msk);
            db += __shfl_xor(db, msk);
            cr += __shfl_xor(cr, msk);
            ci += __shfl_xor(ci, msk);
        }
        if (dl == 0) {
            atomicAdd(&ws[0 * NB * MBINS + bb * MBINS + k0], da);
            atomicAdd(&ws[1 * NB * MBINS + bb * MBINS + k0], db);
            atomicAdd(&ws[2 * NB * MBINS + bb * MBINS + k0], cr);
            atomicAdd(&ws[3 * NB * MBINS + bb * MBINS + k0], ci);
        }
    }
}

// Inverse: block = (b, dir). S = C/den (dir 0) or conj(C)/den (dir 1), padded to 4096,
// radix-4 IFFT (conj twiddles, digit-reversed output indexing), real part.
__global__ __launch_bounds__(512)
void cte_inv_kernel(const float* __restrict__ ws, float* __restrict__ out) {
    __shared__ float2 zz[4096];       // 32 KB
    __shared__ float2 tw[1024];       // tw[e] = exp(+2*pi*i*e/4096)
    const int tid = threadIdx.x;
    const int bb  = blockIdx.x >> 1;
    const int dir = blockIdx.x & 1;

    for (int i = tid; i < 1024; i += 512) {
        float s, c;
        sincosf(6.283185307179586f * (float)i * (1.0f / 4096.0f), &s, &c);
        tw[i] = make_float2(c, s);
    }
    for (int i = tid; i < 4096; i += 512) {
        float2 v = make_float2(0.f, 0.f);
        if (i < MBINS) {
            float den = ws[(dir ? 1 : 0) * NB * MBINS + bb * MBINS + i] + LMBDA;
            float cr  = ws[2 * NB * MBINS + bb * MBINS + i];
            float ci  = ws[3 * NB * MBINS + bb * MBINS + i];
            if (dir) ci = -ci;
            v = make_float2(cr / den, ci / den);
        }
        zz[i] = v;
    }
    __syncthreads();

#pragma unroll
    for (int st = 0; st < 6; ++st) {
        const int lgm  = 10 - 2 * st;     // m = 1024,256,64,16,4,1
        const int m    = 1 << lgm;
        const int step = 1024 >> lgm;     // 4096/(4m)
#pragma unroll
        for (int r = 0; r < 2; ++r) {
            int bf = r * 512 + tid;       // butterfly id [0,1024)
            int j  = bf & (m - 1);
            int i0 = ((bf >> lgm) << (lgm + 2)) + j;
            float2 a0 = zz[i0], a1 = zz[i0 + m], a2 = zz[i0 + 2 * m], a3 = zz[i0 + 3 * m];
            float2 t0  = caddf(a0, a2), t1v = csubf(a0, a2);
            float2 t2v = caddf(a1, a3), t3  = csubf(a1, a3);
            float2 y0 = caddf(t0, t2v);
            float2 y2 = csubf(t0, t2v);
            float2 y1 = make_float2(t1v.x - t3.y, t1v.y + t3.x);   // t1 + i*t3 (inverse)
            float2 y3 = make_float2(t1v.x + t3.y, t1v.y - t3.x);   // t1 - i*t3
            if (m > 1) {
                float2 w1 = tw[j * step];
                float2 w2 = cmulf(w1, w1);
                float2 w3 = cmulf(w2, w1);
                y1 = cmulf(y1, w1);
                y2 = cmulf(y2, w2);
                y3 = cmulf(y3, w3);
            }
            zz[i0] = y0; zz[i0 + m] = y1; zz[i0 + 2 * m] = y2; zz[i0 + 3 * m] = y3;
        }
        __syncthreads();
    }

    const float scale = 1.0f / 4096.0f;
    for (int t = tid; t < 4096; t += 512) {
        int rt = rev4_12(t);              // R[t] sits at digit-reversed slot
        float val = zz[rt].x * scale;
        int col = (dir == 0) ? (4095 - t) : (4096 + t);
        out[(size_t)bb * 8192 + col] = val;
    }
}

extern "C" void kernel_launch(void* const* d_in, const int* in_sizes, int n_in,
                              void* d_out, int out_size, void* d_ws, size_t ws_size,
                              hipStream_t stream) {
    const float* a = (const float*)d_in[0];
    const float* b = (const float*)d_in[1];
    // d_in[2] (offsets) only determines shapes; numerically unused.
    float* out = (float*)d_out;
    float* ws  = (float*)d_ws;

    hipMemsetAsync(d_ws, 0, 4 * NB * MBINS * sizeof(float), stream);
    cte_fwd_kernel<<<dim3(NB * (ND / DLB)), dim3(FWD_THREADS), 0, stream>>>(a, b, ws);
    cte_inv_kernel<<<dim3(NB * 2), dim3(512), 0, stream>>>(ws, out);
}

// Round 11
// 189.311 us; speedup vs baseline: 5.2054x; 5.2054x over previous
//
#include <hip/hip_runtime.h>

#define NB 16
#define LT 4096
#define ND 512
#define MBINS 1024
#define LMBDA 0.1f
#define DLB 8                 // d-channels per fwd block
#define FWD_THREADS 1024

__device__ __forceinline__ float2 cmulf(float2 a, float2 b) {
    return make_float2(a.x * b.x - a.y * b.y, a.x * b.y + a.y * b.x);
}
__device__ __forceinline__ float2 caddf(float2 a, float2 b) { return make_float2(a.x + b.x, a.y + b.y); }
__device__ __forceinline__ float2 csubf(float2 a, float2 b) { return make_float2(a.x - b.x, a.y - b.y); }

// base-4 digit reversal of a 10-bit index (bit-reverse, then swap adjacent bit pairs)
__device__ __forceinline__ int rev4_10(int k) {
    unsigned r = __brev((unsigned)k) >> 22;
    return (int)(((r & 0x155u) << 1) | ((r >> 1) & 0x155u));
}
// base-4 digit reversal of a 12-bit index
__device__ __forceinline__ int rev4_12(int t) {
    unsigned r = __brev((unsigned)t) >> 20;
    return (int)(((r & 0x555u) << 1) | ((r >> 1) & 0x555u));
}

// ws layout: float [4][NB][MBINS] : 0 -> sum|Qa|^2, 1 -> sum|Qb|^2, 2 -> Re C, 3 -> Im C
// where C = sum_d conj(Qa)*Qb.

// Forward: block = (batch, 8 consecutive d), 1024 threads. Real-pack z = a + i*b.
// == R5 champion structure == (stage-1-in-registers, XCD swizzle, incremental-twiddle
// combine) with plain [1024 row][8 col] LDS layout (ZS=9 pad worsened conflicts).
// LDS stage loop runs FOUR stages m=64,16,4,1 (R10 regression: dropped m=1 while
// keeping the combine that expects the completed FFT -- wrong results).
// Middle-stage and stage-1 row offsets are compile-time immediates (ds imm offsets).
__global__ __launch_bounds__(FWD_THREADS)
void cte_fwd_kernel(const float* __restrict__ A, const float* __restrict__ Bp,
                    float* __restrict__ ws) {
    __shared__ float2 z[8192];         // [1024 rows][8 cols]; 64 KB
    __shared__ float2 tw[256];         // tw[e] = exp(-2*pi*i*e/1024), e<256; 2 KB

    const int tid = threadIdx.x;
    // XCD-aware swizzle: line-sharing chunk pairs (2c,2c+1) -> same XCD, adjacent slots.
    const int logical = (blockIdx.x & 7) * (gridDim.x >> 3) + (blockIdx.x >> 3);
    const int bb    = logical >> 6;           // 16 batches
    const int chunk = logical & 63;           // 64 d-chunks of 8
    const int d0    = chunk * DLB;

    if (tid < 256) {
        float s, c;
        sincosf(-6.283185307179586f * (float)tid * (1.0f / 1024.0f), &s, &c);
        tw[tid] = make_float2(c, s);
    }

    const int dl  = tid & 7;          // d lane
    const int g   = tid >> 3;         // k-group 0..127
    const int dp  = tid & 3;          // d-pair for the load/stage1 phase
    const int t1l = tid >> 2;         // [0,256): stage-1 butterfly row

    float2 X1[8], Z4[8];              // X[k] and X[(4096-k)%4096], k = g + 128*j
#pragma unroll
    for (int j = 0; j < 8; ++j) {
        X1[j] = make_float2(0.f, 0.f);
        Z4[j] = make_float2(0.f, 0.f);
    }

    for (int t2 = 0; t2 < 4; ++t2) {
        __syncthreads();  // previous round's combine reads of z done; tw valid (round 0)

        // ---- load 4 rows (t1l + 256*it) + radix-4 stage 1 (m=256) in registers ----
        float2 A4[4], B4[4];
#pragma unroll
        for (int it = 0; it < 4; ++it) {
            size_t off = ((size_t)(bb * LT + 4 * (t1l + 256 * it) + t2)) * ND + d0 + 2 * dp;
            A4[it] = *(const float2*)(A + off);
            B4[it] = *(const float2*)(Bp + off);
        }
        {
            float2 w1 = tw[t1l];
            float2 w2 = cmulf(w1, w1);
            float2 w3 = cmulf(w2, w1);
#pragma unroll
            for (int c = 0; c < 2; ++c) {
                float2 x0 = c ? make_float2(A4[0].y, B4[0].y) : make_float2(A4[0].x, B4[0].x);
                float2 x1 = c ? make_float2(A4[1].y, B4[1].y) : make_float2(A4[1].x, B4[1].x);
                float2 x2 = c ? make_float2(A4[2].y, B4[2].y) : make_float2(A4[2].x, B4[2].x);
                float2 x3 = c ? make_float2(A4[3].y, B4[3].y) : make_float2(A4[3].x, B4[3].x);
                float2 t0  = caddf(x0, x2), t1v = csubf(x0, x2);
                float2 t2v = caddf(x1, x3), t3  = csubf(x1, x3);
                float2 y0 = caddf(t0, t2v);
                float2 y2 = cmulf(csubf(t0, t2v), w2);
                float2 y1 = cmulf(make_float2(t1v.x + t3.y, t1v.y - t3.x), w1);  // (t1 - i*t3)*w1
                float2 y3 = cmulf(make_float2(t1v.x - t3.y, t1v.y + t3.x), w3);  // (t1 + i*t3)*w3
                int ix = (t1l << 3) + 2 * dp + c;
                z[ix]        = y0;
                z[ix + 2048] = y1;     // row +256
                z[ix + 4096] = y2;     // row +512
                z[ix + 6144] = y3;     // row +768
            }
        }
        __syncthreads();

        // ---- remaining radix-4 DIF stages (m = 64,16,4,1), batched over 8 d ----
        // (m=1: j=0, tw[0]=(1,0) -> generic butterfly is exact; completes the FFT.)
#pragma unroll
        for (int st = 0; st < 4; ++st) {
            const int lgm  = 6 - 2 * st;      // 6,4,2,0
            const int m    = 1 << lgm;
            const int step = 256 >> lgm;      // 1024/(4m)
#pragma unroll
            for (int r2 = 0; r2 < 2; ++r2) {
                int u   = r2 * FWD_THREADS + tid;  // 2048 work items
                int dli = u & 7;
                int bf  = u >> 3;                  // butterfly id [0,256)
                int j   = bf & (m - 1);
                int i0  = ((bf >> lgm) << (lgm + 2)) + j;
                int ix  = (i0 << 3) + dli;         // rows +m,+2m,+3m -> imm offsets
                float2 a0 = z[ix];
                float2 a1 = z[ix + 8 * m];
                float2 a2 = z[ix + 16 * m];
                float2 a3 = z[ix + 24 * m];
                float2 t0  = caddf(a0, a2), t1v = csubf(a0, a2);
                float2 t2v = caddf(a1, a3), t3  = csubf(a1, a3);
                float2 w1 = tw[j * step];
                float2 w2 = cmulf(w1, w1);
                float2 w3 = cmulf(w2, w1);
                z[ix]          = caddf(t0, t2v);
                z[ix + 8 * m]  = cmulf(make_float2(t1v.x + t3.y, t1v.y - t3.x), w1);
                z[ix + 16 * m] = cmulf(csubf(t0, t2v), w2);
                z[ix + 24 * m] = cmulf(make_float2(t1v.x - t3.y, t1v.y + t3.x), w3);
            }
            __syncthreads();
        }

        // ---- combine: X[k] += W4096^(t2*k)*Y[k]; X[4096-k] += conj(W)*Y[(1024-k)%1024] ----
        // Incremental twiddle: w(k=g+128j) = w0 * wstep^j (2 sincosf per round)
        float2 w, wstep;
        {
            float s, c;
            sincosf(-1.5339807878856412e-03f * (float)(t2 * g), &s, &c);  // -2pi/4096 * t2*g
            w = make_float2(c, s);
            sincosf(-1.9634954084936207e-01f * (float)t2, &s, &c);        // -2pi/4096 * 128*t2
            wstep = make_float2(c, s);
        }
#pragma unroll
        for (int j = 0; j < 8; ++j) {
            int k   = g + 128 * j;
            int rk  = rev4_10(k);
            int k2  = (1024 - k) & 1023;
            int rk2 = rev4_10(k2);
            float2 Ya = z[(rk << 3) + dl];
            float2 Yb = z[(rk2 << 3) + dl];
            X1[j].x += w.x * Ya.x - w.y * Ya.y;
            X1[j].y += w.x * Ya.y + w.y * Ya.x;
            Z4[j].x += w.x * Yb.x + w.y * Yb.y;   // conj(w) * Yb
            Z4[j].y += w.x * Yb.y - w.y * Yb.x;
            w = cmulf(w, wstep);
        }
    }

    // ---- unpack Qa/Qb, products, reduce over 8 d-lanes, atomic flush ----
#pragma unroll
    for (int j = 0; j < 8; ++j) {
        int k = g + 128 * j;
        float Ar = 0.5f * (X1[j].x + Z4[j].x);
        float Ai = 0.5f * (X1[j].y - Z4[j].y);
        float Br = 0.5f * (X1[j].y + Z4[j].y);
        float Bi = 0.5f * (Z4[j].x - X1[j].x);
        float da = Ar * Ar + Ai * Ai;
        float db = Br * Br + Bi * Bi;
        float cr = Ar * Br + Ai * Bi;
        float ci = Ar * Bi - Ai * Br;
        for (int msk = 1; msk < DLB; msk <<= 1) {
            da += __shfl_xor(da, msk);
            db += __shfl_xor(db, msk);
            cr += __shfl_xor(cr, msk);
            ci += __shfl_xor(ci, msk);
        }
        if (dl == 0) {
            atomicAdd(&ws[0 * NB * MBINS + bb * MBINS + k], da);
            atomicAdd(&ws[1 * NB * MBINS + bb * MBINS + k], db);
            atomicAdd(&ws[2 * NB * MBINS + bb * MBINS + k], cr);
            atomicAdd(&ws[3 * NB * MBINS + bb * MBINS + k], ci);
        }
    }
}

// Inverse: block = (b, dir). S = C/den (dir 0) or conj(C)/den (dir 1), padded to 4096,
// radix-4 IFFT (conj twiddles, digit-reversed output indexing), real part.
__global__ __launch_bounds__(512)
void cte_inv_kernel(const float* __restrict__ ws, float* __restrict__ out) {
    __shared__ float2 zz[4096];       // 32 KB
    __shared__ float2 tw[1024];       // tw[e] = exp(+2*pi*i*e/4096)
    const int tid = threadIdx.x;
    const int bb  = blockIdx.x >> 1;
    const int dir = blockIdx.x & 1;

    for (int i = tid; i < 1024; i += 512) {
        float s, c;
        sincosf(6.283185307179586f * (float)i * (1.0f / 4096.0f), &s, &c);
        tw[i] = make_float2(c, s);
    }
    for (int i = tid; i < 4096; i += 512) {
        float2 v = make_float2(0.f, 0.f);
        if (i < MBINS) {
            float den = ws[(dir ? 1 : 0) * NB * MBINS + bb * MBINS + i] + LMBDA;
            float cr  = ws[2 * NB * MBINS + bb * MBINS + i];
            float ci  = ws[3 * NB * MBINS + bb * MBINS + i];
            if (dir) ci = -ci;
            v = make_float2(cr / den, ci / den);
        }
        zz[i] = v;
    }
    __syncthreads();

#pragma unroll
    for (int st = 0; st < 6; ++st) {
        const int lgm  = 10 - 2 * st;     // m = 1024,256,64,16,4,1
        const int m    = 1 << lgm;
        const int step = 1024 >> lgm;     // 4096/(4m)
#pragma unroll
        for (int r = 0; r < 2; ++r) {
            int bf = r * 512 + tid;       // butterfly id [0,1024)
            int j  = bf & (m - 1);
            int i0 = ((bf >> lgm) << (lgm + 2)) + j;
            float2 a0 = zz[i0], a1 = zz[i0 + m], a2 = zz[i0 + 2 * m], a3 = zz[i0 + 3 * m];
            float2 t0  = caddf(a0, a2), t1v = csubf(a0, a2);
            float2 t2v = caddf(a1, a3), t3  = csubf(a1, a3);
            float2 y0 = caddf(t0, t2v);
            float2 y2 = csubf(t0, t2v);
            float2 y1 = make_float2(t1v.x - t3.y, t1v.y + t3.x);   // t1 + i*t3 (inverse)
            float2 y3 = make_float2(t1v.x + t3.y, t1v.y - t3.x);   // t1 - i*t3
            if (m > 1) {
                float2 w1 = tw[j * step];
                float2 w2 = cmulf(w1, w1);
                float2 w3 = cmulf(w2, w1);
                y1 = cmulf(y1, w1);
                y2 = cmulf(y2, w2);
                y3 = cmulf(y3, w3);
            }
            zz[i0] = y0; zz[i0 + m] = y1; zz[i0 + 2 * m] = y2; zz[i0 + 3 * m] = y3;
        }
        __syncthreads();
    }

    const float scale = 1.0f / 4096.0f;
    for (int t = tid; t < 4096; t += 512) {
        int rt = rev4_12(t);              // R[t] sits at digit-reversed slot
        float val = zz[rt].x * scale;
        int col = (dir == 0) ? (4095 - t) : (4096 + t);
        out[(size_t)bb * 8192 + col] = val;
    }
}

extern "C" void kernel_launch(void* const* d_in, const int* in_sizes, int n_in,
                              void* d_out, int out_size, void* d_ws, size_t ws_size,
                              hipStream_t stream) {
    const float* a = (const float*)d_in[0];
    const float* b = (const float*)d_in[1];
    // d_in[2] (offsets) only determines shapes; numerically unused.
    float* out = (float*)d_out;
    float* ws  = (float*)d_ws;

    hipMemsetAsync(d_ws, 0, 4 * NB * MBINS * sizeof(float), stream);
    cte_fwd_kernel<<<dim3(NB * (ND / DLB)), dim3(FWD_THREADS), 0, stream>>>(a, b, ws);
    cte_inv_kernel<<<dim3(NB * 2), dim3(512), 0, stream>>>(ws, out);
}